// Round 10
// baseline (407.455 us; speedup 1.0000x reference)
//
#include <hip/hip_runtime.h>
#include <math.h>

#define B_ 8
#define T_ 1024
#define C_ 768
#define H_ 8
#define D_ 96
#define M_ (B_ * T_)     // 8192 tokens
#define N1_ (3 * C_)     // 2304
#define KD_ 768          // K of both GEMMs

typedef __bf16 bf16x8 __attribute__((ext_vector_type(8)));
typedef float f32x4 __attribute__((ext_vector_type(4)));
typedef float f32x16 __attribute__((ext_vector_type(16)));

__device__ __forceinline__ unsigned short f2bf(float f) {
  unsigned int u = __float_as_uint(f);
  u += 0x7FFF + ((u >> 16) & 1);          // round-to-nearest-even
  return (unsigned short)(u >> 16);
}

// async global->LDS, 16B per lane; LDS dest = uniform base + lane*16
__device__ __forceinline__ void load_lds16(const void* g, void* l) {
  __builtin_amdgcn_global_load_lds(
      (const __attribute__((address_space(1))) unsigned int*)g,
      (__attribute__((address_space(3))) unsigned int*)l, 16, 0, 0);
}

// ---------------------------------------------------------------------------
// fp32 -> bf16 elementwise (for x)
// ---------------------------------------------------------------------------
__global__ __launch_bounds__(256) void cvt_bf16_kernel(
    const float* __restrict__ in, unsigned short* __restrict__ out, int n) {
  int i = (blockIdx.x * 256 + threadIdx.x) * 4;
  if (i + 3 < n) {
    float4 v = *(const float4*)(in + i);
    ushort4 o;
    o.x = f2bf(v.x); o.y = f2bf(v.y); o.z = f2bf(v.z); o.w = f2bf(v.w);
    *(ushort4*)(out + i) = o;
  }
}

// ---------------------------------------------------------------------------
// Both weight transposes in one launch. W [Kd][Nd] fp32 -> WT [Nd][Kd] bf16.
// ---------------------------------------------------------------------------
__global__ __launch_bounds__(256) void w_transpose2_kernel(
    const float* __restrict__ Wa, unsigned short* __restrict__ WaT,
    const float* __restrict__ Wp, unsigned short* __restrict__ WpT) {
  __shared__ float Lt[32][33];
  int bid = blockIdx.x;
  const float* W; unsigned short* WT; int Nd;
  if (bid < 1728) { W = Wa; WT = WaT; Nd = N1_; }
  else            { W = Wp; WT = WpT; Nd = C_; bid -= 1728; }
  const int r0 = (bid % 24) * 32;   // Kd
  const int c0 = (bid / 24) * 32;   // Nd
#pragma unroll
  for (int i = 0; i < 4; ++i) {
    int e = threadIdx.x + 256 * i;
    int r = e >> 5, c = e & 31;
    Lt[r][c] = W[(size_t)(r0 + r) * Nd + c0 + c];
  }
  __syncthreads();
#pragma unroll
  for (int i = 0; i < 4; ++i) {
    int e = threadIdx.x + 256 * i;
    int rr = e >> 5, cc = e & 31;
    WT[(size_t)(c0 + rr) * KD_ + r0 + cc] = f2bf(Lt[cc][rr]);
  }
}

// ---------------------------------------------------------------------------
// Producer-consumer bf16 MFMA GEMM (32x32x16), barrier-free K-loop.
// __launch_bounds__(384, 2): VGPR cap 256 so producer rv[2][CPP] and consumer
// acc do NOT spill (R4/R9 failure mode: default heuristic capped ~52-96).
// 384 thr: waves 0-3 consume (2x2 of 32x32 per kh), waves 4-5 produce
// (global->VGPR ping-pong -> ds_write into a 4-stage LDS ring).
// Monotonic LDS flags; no __syncthreads in the loop -> no vmcnt(0) drain.
// Tile (WM32*64) x 128. A/B frag: lane l = [row=l&31][k=(l>>5)*8..+7].
// C/D: col = lane&31, row = (r&3)+8*(r>>2)+4*(lane>>5)  [m74/m101].
// VSCAT (qkv): col >= 1536 (V) scatters to vt[bh][d][t].
// ---------------------------------------------------------------------------
template <int WM32, bool OUTF32, bool VSCAT>
__global__ __launch_bounds__(384, 2) void gemm_pc_kernel(
    const unsigned short* __restrict__ A, const unsigned short* __restrict__ Bt,
    const float* __restrict__ bias, void* __restrict__ Cout,
    unsigned short* __restrict__ vt, int N,
    int sc_lim, float sc, int mmask, int mshift) {
  constexpr int AS2  = 2 * WM32;       // A 32-row blocks per tile
  constexpr int NCH  = AS2 * 2 + 8;    // 1KB chunks per stage
  constexpr int S    = 4;              // ring stages
  constexpr int CPP  = NCH / 2;        // chunks per producer wave
  constexpr int NITER = KD_ / 32;      // 24
  __shared__ __align__(16) unsigned short Sb[S][NCH * 512];
  __shared__ int flg[2 * S];           // producer p stage s -> flg[p*S+s]
  __shared__ int done[4];

  const int tid = threadIdx.x;
  const int w = tid >> 6, l = tid & 63;
  const int l31 = l & 31, lh = l >> 5;
  const int bid = blockIdx.x;
  const int m0 = (bid & mmask) * (AS2 * 32), n0 = (bid >> mshift) * 128;

  if (tid < 2 * S) flg[tid] = 0;
  if (tid < 4) done[tid] = 0;
  __syncthreads();  // only barrier (flag init)

  if (w < 4) {
    // ---------------- consumers ----------------
    const int wrb = (w >> 1) * WM32;
    const int wnb = (w & 1) * 2;
    f32x16 acc[WM32][2];
#pragma unroll
    for (int i = 0; i < WM32; ++i)
#pragma unroll
      for (int j = 0; j < 2; ++j)
#pragma unroll
        for (int r = 0; r < 16; ++r) acc[i][j][r] = 0.f;

    for (int k = 0; k < NITER; ++k) {
      const int s = k % S;
      while (*(volatile int*)&flg[0 * S + s] < k + 1) __builtin_amdgcn_s_sleep(1);
      while (*(volatile int*)&flg[1 * S + s] < k + 1) __builtin_amdgcn_s_sleep(1);
      __asm__ __volatile__("" ::: "memory");  // no ds_read hoisting above spin
#pragma unroll
      for (int kh = 0; kh < 2; ++kh) {
        bf16x8 af[WM32], bfr[2];
#pragma unroll
        for (int mi = 0; mi < WM32; ++mi)
          af[mi] = *(const bf16x8*)&Sb[s][((wrb + mi) * 2 + kh) * 512 + l * 8];
#pragma unroll
        for (int ni = 0; ni < 2; ++ni)
          bfr[ni] = *(const bf16x8*)&Sb[s][((AS2 + wnb + ni) * 2 + kh) * 512 + l * 8];
#pragma unroll
        for (int mi = 0; mi < WM32; ++mi)
#pragma unroll
          for (int ni = 0; ni < 2; ++ni)
            acc[mi][ni] = __builtin_amdgcn_mfma_f32_32x32x16_bf16(
                af[mi], bfr[ni], acc[mi][ni], 0, 0, 0);
      }
      __asm__ __volatile__("" ::: "memory");  // done-write stays after reads
      if (l == 0) *(volatile int*)&done[w] = k + 1;
    }

    const bool vblock = VSCAT && (n0 >= 1536);
#pragma unroll
    for (int mi = 0; mi < WM32; ++mi) {
      const int rowb = m0 + (wrb + mi) * 32 + 4 * lh;
#pragma unroll
      for (int ni = 0; ni < 2; ++ni) {
        const int col = n0 + (wnb + ni) * 32 + l31;
        const float bv = bias[col];
        if (!vblock) {
          const float mul = (col < sc_lim) ? sc : 1.f;
#pragma unroll
          for (int r = 0; r < 16; ++r) {
            const int row = rowb + (r & 3) + 8 * (r >> 2);
            float v = (acc[mi][ni][r] + bv) * mul;
            if (OUTF32)
              ((float*)Cout)[(size_t)row * N + col] = v;
            else
              ((unsigned short*)Cout)[(size_t)row * N + col] = f2bf(v);
          }
        } else {
          const int x = col - 1536;
          const int h = x / 96, d = x % 96;
#pragma unroll
          for (int r = 0; r < 16; ++r) {
            const int row = rowb + (r & 3) + 8 * (r >> 2);
            const int bb = row >> 10, t = row & 1023;
            vt[((size_t)(bb * H_ + h) * D_ + d) * T_ + t] =
                f2bf(acc[mi][ni][r] + bv);
          }
        }
      }
    }
  } else {
    // ---------------- producers ----------------
    const int pw = w - 4;  // 0,1
    const unsigned short* gp[CPP];
#pragma unroll
    for (int i = 0; i < CPP; ++i) {
      const int c = pw * CPP + i;
      const int pr = c >> 1, kh = c & 1;
      gp[i] = (pr < AS2)
          ? A  + (size_t)(m0 + pr * 32 + l31) * KD_ + kh * 16 + lh * 8
          : Bt + (size_t)(n0 + (pr - AS2) * 32 + l31) * KD_ + kh * 16 + lh * 8;
    }
    uint4 rv[2][CPP];
#pragma unroll
    for (int i = 0; i < CPP; ++i) { rv[0][i] = *(const uint4*)gp[i]; gp[i] += 32; }
#pragma unroll
    for (int i = 0; i < CPP; ++i) { rv[1][i] = *(const uint4*)gp[i]; gp[i] += 32; }

    for (int k = 0; k < NITER; ++k) {
      const int s = k % S;
      if (k >= S) {
        const int need = k - S + 1;  // consumers done with iter k-S
        for (;;) {
          int d0 = *(volatile int*)&done[0];
          int d1 = *(volatile int*)&done[1];
          int d2 = *(volatile int*)&done[2];
          int d3 = *(volatile int*)&done[3];
          if (min(min(d0, d1), min(d2, d3)) >= need) break;
          __builtin_amdgcn_s_sleep(1);
        }
      }
      __asm__ __volatile__("" ::: "memory");
#pragma unroll
      for (int i = 0; i < CPP; ++i)
        *(uint4*)&Sb[s][(pw * CPP + i) * 512 + l * 8] = rv[k & 1][i];
      __asm__ __volatile__("" ::: "memory");  // flag stays after data (ds in-order)
      if (l == 0) *(volatile int*)&flg[pw * S + s] = k + 1;
      if (k + 2 < NITER) {
#pragma unroll
        for (int i = 0; i < CPP; ++i) { rv[k & 1][i] = *(const uint4*)gp[i]; gp[i] += 32; }
      }
    }
  }
}

// ---------------------------------------------------------------------------
// Flash causal attention (unchanged R8): bf16 MFMA 16x16x32, max-free softmax
// (Q pre-scaled), l via ones-MFMA, paired q-tiles (17 key-tiles/block),
// K/V double-buffered LDS, XCD swizzle bh = id & 63.
// ---------------------------------------------------------------------------
__global__ __launch_bounds__(256) void attn_mfma_kernel(
    const unsigned short* __restrict__ qkv,  // [8192][2304], Q pre-scaled
    const unsigned short* __restrict__ vt,   // [64][96][1024]
    unsigned short* __restrict__ y) {        // [8192][768]
  __shared__ __align__(16) unsigned short KV[2][24 * 512];  // 48 KB
  __shared__ __align__(16) unsigned short Pt[4][16][72];    // pad 64->72

  const int tid = threadIdx.x;
  const int w = tid >> 6, l = tid & 63;
  const int lm = l & 15, lq = l >> 4;
  const int bh = blockIdx.x & 63, pi = blockIdx.x >> 6;
  const int b = bh >> 3, h = bh & 7;
  const size_t bT = (size_t)b * T_;

  bf16x8 onef;
#pragma unroll
  for (int i = 0; i < 8; ++i) onef[i] = (__bf16)1.0f;

  auto issue = [&](int j0, int buf) {
#pragma unroll
    for (int i = 0; i < 6; ++i) {
      const int c = w * 6 + i;
      const unsigned short* g;
      if (c < 12) {
        const int kc = c >> 2, nb = c & 3;
        g = qkv + (bT + j0 + nb * 16 + lm) * N1_ + C_ + h * D_ + kc * 32 + lq * 8;
      } else {
        const int cv = c - 12;
        const int db = cv >> 1, vc = cv & 1;
        g = vt + ((size_t)bh * D_ + db * 16 + lm) * T_ + j0 + vc * 32 + lq * 8;
      }
      load_lds16(g, &KV[buf][c * 512]);
    }
  };

  int cur = 0;
  issue(0, 0);

  for (int half = 0; half < 2; ++half) {
    const int qt = half ? (15 - pi) : pi;
    const int q0 = qt * 64;

    bf16x8 qf[3];
    {
      const unsigned short* qp =
          qkv + (bT + q0 + w * 16 + lm) * N1_ + h * D_ + lq * 8;
      qf[0] = *(const bf16x8*)(qp);
      qf[1] = *(const bf16x8*)(qp + 32);
      qf[2] = *(const bf16x8*)(qp + 64);
    }
    f32x4 o[7];
#pragma unroll
    for (int i = 0; i < 7; ++i) o[i] = (f32x4){0.f, 0.f, 0.f, 0.f};

    for (int jt = 0; jt <= qt; ++jt) {
      __syncthreads();
      if (jt < qt)          issue((jt + 1) * 64, cur ^ 1);
      else if (half == 0)   issue(0, cur ^ 1);

      const bool diag = (jt == qt);
#pragma unroll
      for (int nb = 0; nb < 4; ++nb) {
        if (diag && nb > w) {
#pragma unroll
          for (int r = 0; r < 4; ++r)
            Pt[w][lq * 4 + r][nb * 16 + lm] = 0;
          continue;
        }
        f32x4 a = (f32x4){0.f, 0.f, 0.f, 0.f};
#pragma unroll
        for (int kc = 0; kc < 3; ++kc) {
          bf16x8 kf = *(const bf16x8*)&KV[cur][(kc * 4 + nb) * 512 + l * 8];
          a = __builtin_amdgcn_mfma_f32_16x16x32_bf16(qf[kc], kf, a, 0, 0, 0);
        }
#pragma unroll
        for (int r = 0; r < 4; ++r) {
          float s = a[r];
          if (diag && (nb * 16 + lm > w * 16 + lq * 4 + r)) s = -INFINITY;
          Pt[w][lq * 4 + r][nb * 16 + lm] = f2bf(__expf(s));
        }
      }

      bf16x8 pf0 = *(const bf16x8*)&Pt[w][lm][lq * 8];
      bf16x8 pf1 = *(const bf16x8*)&Pt[w][lm][32 + lq * 8];
#pragma unroll
      for (int db = 0; db < 6; ++db) {
        bf16x8 vf0 = *(const bf16x8*)&KV[cur][(12 + db * 2 + 0) * 512 + l * 8];
        bf16x8 vf1 = *(const bf16x8*)&KV[cur][(12 + db * 2 + 1) * 512 + l * 8];
        o[db] = __builtin_amdgcn_mfma_f32_16x16x32_bf16(pf0, vf0, o[db], 0, 0, 0);
        o[db] = __builtin_amdgcn_mfma_f32_16x16x32_bf16(pf1, vf1, o[db], 0, 0, 0);
      }
      o[6] = __builtin_amdgcn_mfma_f32_16x16x32_bf16(pf0, onef, o[6], 0, 0, 0);
      o[6] = __builtin_amdgcn_mfma_f32_16x16x32_bf16(pf1, onef, o[6], 0, 0, 0);
      cur ^= 1;
    }

#pragma unroll
    for (int r = 0; r < 4; ++r) {
      const float inv = 1.f / o[6][r];
      const size_t row = bT + q0 + w * 16 + lq * 4 + r;
#pragma unroll
      for (int db = 0; db < 6; ++db)
        y[row * C_ + h * D_ + db * 16 + lm] = f2bf(o[db][r] * inv);
    }
  }
}

// ---------------------------------------------------------------------------
extern "C" void kernel_launch(void* const* d_in, const int* in_sizes, int n_in,
                              void* d_out, int out_size, void* d_ws, size_t ws_size,
                              hipStream_t stream) {
  const float* x      = (const float*)d_in[0];
  const float* W_attn = (const float*)d_in[1];
  const float* b_attn = (const float*)d_in[2];
  const float* W_proj = (const float*)d_in[3];
  const float* b_proj = (const float*)d_in[4];
  float* out = (float*)d_out;

  char* ws = (char*)d_ws;
  unsigned short* xb  = (unsigned short*)(ws);                    // 12.58 MB
  unsigned short* WaT = (unsigned short*)(ws + 12582912);         //  3.54 MB
  unsigned short* WpT = (unsigned short*)(ws + 16121856);         //  1.18 MB
  unsigned short* qkv = (unsigned short*)(ws + 17301504);         // 37.75 MB
  unsigned short* vt  = (unsigned short*)(ws + 55050240);         // 12.58 MB
  unsigned short* yb  = (unsigned short*)(ws + 67633152);         // 12.58 MB

  const float qscale = 0.10206207261596577f;  // 1/sqrt(96)

  cvt_bf16_kernel<<<(M_ * C_) / 1024, 256, 0, stream>>>(x, xb, M_ * C_);
  w_transpose2_kernel<<<2304, 256, 0, stream>>>(W_attn, WaT, W_proj, WpT);

  // qkv = x @ W_attn + b_attn (Q cols pre-scaled; V cols scattered to vt)
  gemm_pc_kernel<2, false, true><<<(N1_ / 128) * (M_ / 128), 384, 0, stream>>>(
      xb, WaT, b_attn, qkv, vt, N1_, C_, qscale, 63, 6);
  // attn: 512 blocks, bh = id & 63 for XCD locality
  attn_mfma_kernel<<<8 * B_ * H_, 256, 0, stream>>>(qkv, vt, yb);
  // proj: 64x128 tiles, 128 m-panels
  gemm_pc_kernel<1, true, false><<<(C_ / 128) * (M_ / 64), 384, 0, stream>>>(
      yb, WpT, b_proj, out, nullptr, C_, 0, 1.f, 127, 7);
}

// Round 11
// 363.580 us; speedup vs baseline: 1.1207x; 1.1207x over previous
//
#include <hip/hip_runtime.h>
#include <math.h>

#define B_ 8
#define T_ 1024
#define C_ 768
#define H_ 8
#define D_ 96
#define M_ (B_ * T_)     // 8192 tokens
#define N1_ (3 * C_)     // 2304
#define KD_ 768          // K of both GEMMs
#define NIT 24           // KD_/32

typedef __bf16 bf16x8 __attribute__((ext_vector_type(8)));
typedef float f32x4 __attribute__((ext_vector_type(4)));
typedef float f32x16 __attribute__((ext_vector_type(16)));

__device__ __forceinline__ unsigned short f2bf(float f) {
  unsigned int u = __float_as_uint(f);
  u += 0x7FFF + ((u >> 16) & 1);          // round-to-nearest-even
  return (unsigned short)(u >> 16);
}

// async global->LDS, 16B per lane; LDS dest = uniform base + lane*16
__device__ __forceinline__ void load_lds16(const void* g, void* l) {
  __builtin_amdgcn_global_load_lds(
      (const __attribute__((address_space(1))) unsigned int*)g,
      (__attribute__((address_space(3))) unsigned int*)l, 16, 0, 0);
}

// raw workgroup barrier: NO vmcnt drain (unlike __syncthreads).
// lgkmcnt(0) first so our ds_writes are visible; "memory" clobber pins order.
__device__ __forceinline__ void wg_barrier_lds() {
  __asm__ __volatile__("s_waitcnt lgkmcnt(0)\n\ts_barrier" ::: "memory");
}

// ---------------------------------------------------------------------------
// fp32 -> bf16 elementwise (for x)
// ---------------------------------------------------------------------------
__global__ __launch_bounds__(256) void cvt_bf16_kernel(
    const float* __restrict__ in, unsigned short* __restrict__ out, int n) {
  int i = (blockIdx.x * 256 + threadIdx.x) * 4;
  if (i + 3 < n) {
    float4 v = *(const float4*)(in + i);
    ushort4 o;
    o.x = f2bf(v.x); o.y = f2bf(v.y); o.z = f2bf(v.z); o.w = f2bf(v.w);
    *(ushort4*)(out + i) = o;
  }
}

// ---------------------------------------------------------------------------
// Both weight transposes in one launch. W [Kd][Nd] fp32 -> WT [Nd][Kd] bf16.
// ---------------------------------------------------------------------------
__global__ __launch_bounds__(256) void w_transpose2_kernel(
    const float* __restrict__ Wa, unsigned short* __restrict__ WaT,
    const float* __restrict__ Wp, unsigned short* __restrict__ WpT) {
  __shared__ float Lt[32][33];
  int bid = blockIdx.x;
  const float* W; unsigned short* WT; int Nd;
  if (bid < 1728) { W = Wa; WT = WaT; Nd = N1_; }
  else            { W = Wp; WT = WpT; Nd = C_; bid -= 1728; }
  const int r0 = (bid % 24) * 32;   // Kd
  const int c0 = (bid / 24) * 32;   // Nd
#pragma unroll
  for (int i = 0; i < 4; ++i) {
    int e = threadIdx.x + 256 * i;
    int r = e >> 5, c = e & 31;
    Lt[r][c] = W[(size_t)(r0 + r) * Nd + c0 + c];
  }
  __syncthreads();
#pragma unroll
  for (int i = 0; i < 4; ++i) {
    int e = threadIdx.x + 256 * i;
    int rr = e >> 5, cc = e & 31;
    WT[(size_t)(c0 + rr) * KD_ + r0 + cc] = f2bf(Lt[cc][rr]);
  }
}

// ---------------------------------------------------------------------------
// bf16 MFMA GEMM (32x32x16): raw-barrier pipelined K-loop, VGPR staging.
// Fully-unrolled 24 iters (all reg arrays static -> SSA, no scratch).
// Per iter: ds_write r[k%3] -> LDS[k&1]; issue loads for k+2 -> r[(k+2)%3]
// (stay in flight ACROSS the barrier: only lgkmcnt(0)+s_barrier, no vmcnt
// drain); barrier; ds_read frags + MFMA. One barrier/iter; WAR safe via
// ping-pong (buf reused at k+2, reads complete before barrier k+1).
// Tile (WM32*64) x 128. A/B frag: lane l = [row=l&31][k=(l>>5)*8..+7].
// C/D: col = lane&31, row = (r&3)+8*(r>>2)+4*(lane>>5)  [m74/m101].
// VSCAT (qkv): col >= 1536 (V) scatters to vt[bh][d][t].
// __launch_bounds__(256,2): VGPR cap 256 -> staging+acc fit, no spill.
// ---------------------------------------------------------------------------
template <int WM32, bool OUTF32, bool VSCAT>
__global__ __launch_bounds__(256, 2) void gemm_mfma_kernel(
    const unsigned short* __restrict__ A, const unsigned short* __restrict__ Bt,
    const float* __restrict__ bias, void* __restrict__ Cout,
    unsigned short* __restrict__ vt, int N,
    int sc_lim, float sc, int mmask, int mshift) {
  constexpr int AS2 = 2 * WM32;        // A 32-row blocks per tile
  constexpr int NCH = AS2 * 2 + 8;     // 1KB chunks per buffer
  constexpr int CPW = NCH / 4;         // chunks staged per wave
  __shared__ __align__(16) unsigned short Sb[2][NCH * 512];
  const int tid = threadIdx.x;
  const int w = tid >> 6, l = tid & 63;
  const int l31 = l & 31, lh = l >> 5;
  const int bid = blockIdx.x;
  const int m0 = (bid & mmask) * (AS2 * 32), n0 = (bid >> mshift) * 128;
  const int wrb = (w >> 1) * WM32;     // wave A-block base
  const int wnb = (w & 1) * 2;         // wave B-block base

  f32x16 acc[WM32][2];
#pragma unroll
  for (int i = 0; i < WM32; ++i)
#pragma unroll
    for (int j = 0; j < 2; ++j)
#pragma unroll
      for (int r = 0; r < 16; ++r) acc[i][j][r] = 0.f;

  const unsigned short* gp[CPW];
#pragma unroll
  for (int i = 0; i < CPW; ++i) {
    const int c = w * CPW + i;
    const int pr = c >> 1, kh = c & 1;
    gp[i] = (pr < AS2)
        ? A  + (size_t)(m0 + pr * 32 + l31) * KD_ + kh * 16 + lh * 8
        : Bt + (size_t)(n0 + (pr - AS2) * 32 + l31) * KD_ + kh * 16 + lh * 8;
  }

  uint4 rg[3][CPW];  // depth-2 prefetch ring (static indices only)
#pragma unroll
  for (int i = 0; i < CPW; ++i) { rg[0][i] = *(const uint4*)gp[i]; gp[i] += 32; }
#pragma unroll
  for (int i = 0; i < CPW; ++i) { rg[1][i] = *(const uint4*)gp[i]; gp[i] += 32; }

#pragma unroll
  for (int k = 0; k < NIT; ++k) {
    unsigned short* sb = Sb[k & 1];
    const int cs = k % 3, ns = (k + 2) % 3;
    // write iter-k data (compiler waits precise vmcnt for rg[cs] loads only)
#pragma unroll
    for (int i = 0; i < CPW; ++i)
      *(uint4*)&sb[(w * CPW + i) * 512 + l * 8] = rg[cs][i];
    // issue loads for iter k+2; they stay in flight across the barrier
    if (k + 2 < NIT) {
#pragma unroll
      for (int i = 0; i < CPW; ++i) { rg[ns][i] = *(const uint4*)gp[i]; gp[i] += 32; }
    }
    wg_barrier_lds();  // lgkmcnt(0) + s_barrier, NO vmcnt drain
#pragma unroll
    for (int kh = 0; kh < 2; ++kh) {
      bf16x8 af[WM32], bfr[2];
#pragma unroll
      for (int mi = 0; mi < WM32; ++mi)
        af[mi] = *(const bf16x8*)&sb[((wrb + mi) * 2 + kh) * 512 + l * 8];
#pragma unroll
      for (int ni = 0; ni < 2; ++ni)
        bfr[ni] = *(const bf16x8*)&sb[((AS2 + wnb + ni) * 2 + kh) * 512 + l * 8];
#pragma unroll
      for (int mi = 0; mi < WM32; ++mi)
#pragma unroll
        for (int ni = 0; ni < 2; ++ni)
          acc[mi][ni] = __builtin_amdgcn_mfma_f32_32x32x16_bf16(
              af[mi], bfr[ni], acc[mi][ni], 0, 0, 0);
    }
  }

  const bool vblock = VSCAT && (n0 >= 1536);
#pragma unroll
  for (int mi = 0; mi < WM32; ++mi) {
    const int rowb = m0 + (wrb + mi) * 32 + 4 * lh;
#pragma unroll
    for (int ni = 0; ni < 2; ++ni) {
      const int col = n0 + (wnb + ni) * 32 + l31;
      const float bv = bias[col];
      if (!vblock) {
        const float mul = (col < sc_lim) ? sc : 1.f;
#pragma unroll
        for (int r = 0; r < 16; ++r) {
          const int row = rowb + (r & 3) + 8 * (r >> 2);
          float v = (acc[mi][ni][r] + bv) * mul;
          if (OUTF32)
            ((float*)Cout)[(size_t)row * N + col] = v;
          else
            ((unsigned short*)Cout)[(size_t)row * N + col] = f2bf(v);
        }
      } else {
        const int x = col - 1536;
        const int h = x / 96, d = x % 96;
#pragma unroll
        for (int r = 0; r < 16; ++r) {
          const int row = rowb + (r & 3) + 8 * (r >> 2);
          const int bb = row >> 10, t = row & 1023;
          vt[((size_t)(bb * H_ + h) * D_ + d) * T_ + t] =
              f2bf(acc[mi][ni][r] + bv);
        }
      }
    }
  }
}

// ---------------------------------------------------------------------------
// Flash causal attention (unchanged R8): bf16 MFMA 16x16x32, max-free softmax
// (Q pre-scaled), l via ones-MFMA, paired q-tiles (17 key-tiles/block),
// K/V double-buffered LDS, XCD swizzle bh = id & 63.
// ---------------------------------------------------------------------------
__global__ __launch_bounds__(256) void attn_mfma_kernel(
    const unsigned short* __restrict__ qkv,  // [8192][2304], Q pre-scaled
    const unsigned short* __restrict__ vt,   // [64][96][1024]
    unsigned short* __restrict__ y) {        // [8192][768]
  __shared__ __align__(16) unsigned short KV[2][24 * 512];  // 48 KB
  __shared__ __align__(16) unsigned short Pt[4][16][72];    // pad 64->72

  const int tid = threadIdx.x;
  const int w = tid >> 6, l = tid & 63;
  const int lm = l & 15, lq = l >> 4;
  const int bh = blockIdx.x & 63, pi = blockIdx.x >> 6;
  const int b = bh >> 3, h = bh & 7;
  const size_t bT = (size_t)b * T_;

  bf16x8 onef;
#pragma unroll
  for (int i = 0; i < 8; ++i) onef[i] = (__bf16)1.0f;

  auto issue = [&](int j0, int buf) {
#pragma unroll
    for (int i = 0; i < 6; ++i) {
      const int c = w * 6 + i;
      const unsigned short* g;
      if (c < 12) {
        const int kc = c >> 2, nb = c & 3;
        g = qkv + (bT + j0 + nb * 16 + lm) * N1_ + C_ + h * D_ + kc * 32 + lq * 8;
      } else {
        const int cv = c - 12;
        const int db = cv >> 1, vc = cv & 1;
        g = vt + ((size_t)bh * D_ + db * 16 + lm) * T_ + j0 + vc * 32 + lq * 8;
      }
      load_lds16(g, &KV[buf][c * 512]);
    }
  };

  int cur = 0;
  issue(0, 0);

  for (int half = 0; half < 2; ++half) {
    const int qt = half ? (15 - pi) : pi;
    const int q0 = qt * 64;

    bf16x8 qf[3];
    {
      const unsigned short* qp =
          qkv + (bT + q0 + w * 16 + lm) * N1_ + h * D_ + lq * 8;
      qf[0] = *(const bf16x8*)(qp);
      qf[1] = *(const bf16x8*)(qp + 32);
      qf[2] = *(const bf16x8*)(qp + 64);
    }
    f32x4 o[7];
#pragma unroll
    for (int i = 0; i < 7; ++i) o[i] = (f32x4){0.f, 0.f, 0.f, 0.f};

    for (int jt = 0; jt <= qt; ++jt) {
      __syncthreads();
      if (jt < qt)          issue((jt + 1) * 64, cur ^ 1);
      else if (half == 0)   issue(0, cur ^ 1);

      const bool diag = (jt == qt);
#pragma unroll
      for (int nb = 0; nb < 4; ++nb) {
        if (diag && nb > w) {
#pragma unroll
          for (int r = 0; r < 4; ++r)
            Pt[w][lq * 4 + r][nb * 16 + lm] = 0;
          continue;
        }
        f32x4 a = (f32x4){0.f, 0.f, 0.f, 0.f};
#pragma unroll
        for (int kc = 0; kc < 3; ++kc) {
          bf16x8 kf = *(const bf16x8*)&KV[cur][(kc * 4 + nb) * 512 + l * 8];
          a = __builtin_amdgcn_mfma_f32_16x16x32_bf16(qf[kc], kf, a, 0, 0, 0);
        }
#pragma unroll
        for (int r = 0; r < 4; ++r) {
          float s = a[r];
          if (diag && (nb * 16 + lm > w * 16 + lq * 4 + r)) s = -INFINITY;
          Pt[w][lq * 4 + r][nb * 16 + lm] = f2bf(__expf(s));
        }
      }

      bf16x8 pf0 = *(const bf16x8*)&Pt[w][lm][lq * 8];
      bf16x8 pf1 = *(const bf16x8*)&Pt[w][lm][32 + lq * 8];
#pragma unroll
      for (int db = 0; db < 6; ++db) {
        bf16x8 vf0 = *(const bf16x8*)&KV[cur][(12 + db * 2 + 0) * 512 + l * 8];
        bf16x8 vf1 = *(const bf16x8*)&KV[cur][(12 + db * 2 + 1) * 512 + l * 8];
        o[db] = __builtin_amdgcn_mfma_f32_16x16x32_bf16(pf0, vf0, o[db], 0, 0, 0);
        o[db] = __builtin_amdgcn_mfma_f32_16x16x32_bf16(pf1, vf1, o[db], 0, 0, 0);
      }
      o[6] = __builtin_amdgcn_mfma_f32_16x16x32_bf16(pf0, onef, o[6], 0, 0, 0);
      o[6] = __builtin_amdgcn_mfma_f32_16x16x32_bf16(pf1, onef, o[6], 0, 0, 0);
      cur ^= 1;
    }

#pragma unroll
    for (int r = 0; r < 4; ++r) {
      const float inv = 1.f / o[6][r];
      const size_t row = bT + q0 + w * 16 + lq * 4 + r;
#pragma unroll
      for (int db = 0; db < 6; ++db)
        y[row * C_ + h * D_ + db * 16 + lm] = f2bf(o[db][r] * inv);
    }
  }
}

// ---------------------------------------------------------------------------
extern "C" void kernel_launch(void* const* d_in, const int* in_sizes, int n_in,
                              void* d_out, int out_size, void* d_ws, size_t ws_size,
                              hipStream_t stream) {
  const float* x      = (const float*)d_in[0];
  const float* W_attn = (const float*)d_in[1];
  const float* b_attn = (const float*)d_in[2];
  const float* W_proj = (const float*)d_in[3];
  const float* b_proj = (const float*)d_in[4];
  float* out = (float*)d_out;

  char* ws = (char*)d_ws;
  unsigned short* xb  = (unsigned short*)(ws);                    // 12.58 MB
  unsigned short* WaT = (unsigned short*)(ws + 12582912);         //  3.54 MB
  unsigned short* WpT = (unsigned short*)(ws + 16121856);         //  1.18 MB
  unsigned short* qkv = (unsigned short*)(ws + 17301504);         // 37.75 MB
  unsigned short* vt  = (unsigned short*)(ws + 55050240);         // 12.58 MB
  unsigned short* yb  = (unsigned short*)(ws + 67633152);         // 12.58 MB

  const float qscale = 0.10206207261596577f;  // 1/sqrt(96)

  cvt_bf16_kernel<<<(M_ * C_) / 1024, 256, 0, stream>>>(x, xb, M_ * C_);
  w_transpose2_kernel<<<2304, 256, 0, stream>>>(W_attn, WaT, W_proj, WpT);

  // qkv = x @ W_attn + b_attn (Q cols pre-scaled; V cols scattered to vt)
  gemm_mfma_kernel<2, false, true><<<(N1_ / 128) * (M_ / 128), 256, 0, stream>>>(
      xb, WaT, b_attn, qkv, vt, N1_, C_, qscale, 63, 6);
  // attn: 512 blocks, bh = id & 63 for XCD locality
  attn_mfma_kernel<<<8 * B_ * H_, 256, 0, stream>>>(qkv, vt, yb);
  // proj: 64x128 tiles, 128 m-panels
  gemm_mfma_kernel<1, true, false><<<(C_ / 128) * (M_ / 64), 256, 0, stream>>>(
      yb, WpT, b_proj, out, nullptr, C_, 0, 1.f, 127, 7);
}

// Round 12
// 248.689 us; speedup vs baseline: 1.6384x; 1.4620x over previous
//
#include <hip/hip_runtime.h>
#include <math.h>

#define B_ 8
#define T_ 1024
#define C_ 768
#define H_ 8
#define D_ 96
#define M_ (B_ * T_)     // 8192 tokens
#define N1_ (3 * C_)     // 2304
#define KD_ 768          // K of both GEMMs
#define NIT 24           // KD_/32

typedef __bf16 bf16x8 __attribute__((ext_vector_type(8)));
typedef float f32x4 __attribute__((ext_vector_type(4)));
typedef float f32x16 __attribute__((ext_vector_type(16)));

__device__ __forceinline__ unsigned short f2bf(float f) {
  unsigned int u = __float_as_uint(f);
  u += 0x7FFF + ((u >> 16) & 1);          // round-to-nearest-even
  return (unsigned short)(u >> 16);
}

// async global->LDS, 16B per lane; LDS dest = uniform base + lane*16
__device__ __forceinline__ void load_lds16(const void* g, void* l) {
  __builtin_amdgcn_global_load_lds(
      (const __attribute__((address_space(1))) unsigned int*)g,
      (__attribute__((address_space(3))) unsigned int*)l, 16, 0, 0);
}

// ---------------------------------------------------------------------------
// fp32 -> bf16 elementwise (for x)
// ---------------------------------------------------------------------------
__global__ __launch_bounds__(256) void cvt_bf16_kernel(
    const float* __restrict__ in, unsigned short* __restrict__ out, int n) {
  int i = (blockIdx.x * 256 + threadIdx.x) * 4;
  if (i + 3 < n) {
    float4 v = *(const float4*)(in + i);
    ushort4 o;
    o.x = f2bf(v.x); o.y = f2bf(v.y); o.z = f2bf(v.z); o.w = f2bf(v.w);
    *(ushort4*)(out + i) = o;
  }
}

// ---------------------------------------------------------------------------
// Both weight transposes in one launch. W [Kd][Nd] fp32 -> WT [Nd][Kd] bf16.
// ---------------------------------------------------------------------------
__global__ __launch_bounds__(256) void w_transpose2_kernel(
    const float* __restrict__ Wa, unsigned short* __restrict__ WaT,
    const float* __restrict__ Wp, unsigned short* __restrict__ WpT) {
  __shared__ float Lt[32][33];
  int bid = blockIdx.x;
  const float* W; unsigned short* WT; int Nd;
  if (bid < 1728) { W = Wa; WT = WaT; Nd = N1_; }
  else            { W = Wp; WT = WpT; Nd = C_; bid -= 1728; }
  const int r0 = (bid % 24) * 32;   // Kd
  const int c0 = (bid / 24) * 32;   // Nd
#pragma unroll
  for (int i = 0; i < 4; ++i) {
    int e = threadIdx.x + 256 * i;
    int r = e >> 5, c = e & 31;
    Lt[r][c] = W[(size_t)(r0 + r) * Nd + c0 + c];
  }
  __syncthreads();
#pragma unroll
  for (int i = 0; i < 4; ++i) {
    int e = threadIdx.x + 256 * i;
    int rr = e >> 5, cc = e & 31;
    WT[(size_t)(c0 + rr) * KD_ + r0 + cc] = f2bf(Lt[cc][rr]);
  }
}

// ---------------------------------------------------------------------------
// qkv GEMM: 2-wave (128 thr) blocks, tile 64x128, BK=32 dbuf, 32x32x16 MFMA.
// Small blocks -> ~6 resident/CU (24 KB LDS, 128 reg/wave): barrier stalls of
// one block overlap compute of others (TLP — the R8 structure ran at 2.4).
// LDS chunks (1 KB, frag order): c=pr*2+kh; pr<2 = A 32-row block, pr-2 = B
// 32-col block. A/B frag: lane l = [row=l&31][k=kh*16+(l>>5)*8..+7].
// C/D: col = lane&31, row = (r&3)+8*(r>>2)+4*(lane>>5)  [m74/m101].
// VSCAT: cols >= 1536 (V) scatter to vt[bh][d][t].
// ---------------------------------------------------------------------------
template <bool OUTF32, bool VSCAT>
__global__ __launch_bounds__(128) void gemm2w_kernel(
    const unsigned short* __restrict__ A, const unsigned short* __restrict__ Bt,
    const float* __restrict__ bias, void* __restrict__ Cout,
    unsigned short* __restrict__ vt, int N,
    int sc_lim, float sc, int mmask, int mshift) {
  constexpr int NCH = 12;          // (2 A + 4 B blocks) * 2 kh
  constexpr int CPW = 6;
  __shared__ __align__(16) unsigned short Sb[2][NCH * 512];  // 24 KB
  const int tid = threadIdx.x;
  const int w = tid >> 6, l = tid & 63;
  const int l31 = l & 31, lh = l >> 5;
  const int bid = blockIdx.x;
  const int m0 = (bid & mmask) * 64, n0 = (bid >> mshift) * 128;

  f32x16 acc[2][2];
#pragma unroll
  for (int i = 0; i < 2; ++i)
#pragma unroll
    for (int j = 0; j < 2; ++j)
#pragma unroll
      for (int r = 0; r < 16; ++r) acc[i][j][r] = 0.f;

  const unsigned short* gp[CPW];
#pragma unroll
  for (int i = 0; i < CPW; ++i) {
    const int c = w * CPW + i;
    const int pr = c >> 1, kh = c & 1;
    gp[i] = (pr < 2)
        ? A  + (size_t)(m0 + pr * 32 + l31) * KD_ + kh * 16 + lh * 8
        : Bt + (size_t)(n0 + (pr - 2) * 32 + l31) * KD_ + kh * 16 + lh * 8;
  }

#pragma unroll
  for (int i = 0; i < CPW; ++i) {
    load_lds16(gp[i], &Sb[0][(w * CPW + i) * 512]);
    gp[i] += 32;
  }

  int cur = 0;
  for (int k0 = 0; k0 < KD_; k0 += 32) {
    __syncthreads();  // buf[cur] ready; prev compute done
    if (k0 + 32 < KD_) {
#pragma unroll
      for (int i = 0; i < CPW; ++i) {
        load_lds16(gp[i], &Sb[cur ^ 1][(w * CPW + i) * 512]);
        gp[i] += 32;
      }
    }
#pragma unroll
    for (int kh = 0; kh < 2; ++kh) {
      bf16x8 af[2], bfr[2];
#pragma unroll
      for (int mi = 0; mi < 2; ++mi)
        af[mi] = *(const bf16x8*)&Sb[cur][(mi * 2 + kh) * 512 + l * 8];
#pragma unroll
      for (int ni = 0; ni < 2; ++ni)
        bfr[ni] = *(const bf16x8*)&Sb[cur][(4 + (w * 2 + ni) * 2 + kh) * 512 + l * 8];
#pragma unroll
      for (int mi = 0; mi < 2; ++mi)
#pragma unroll
        for (int ni = 0; ni < 2; ++ni)
          acc[mi][ni] = __builtin_amdgcn_mfma_f32_32x32x16_bf16(
              af[mi], bfr[ni], acc[mi][ni], 0, 0, 0);
    }
    cur ^= 1;
  }

  const bool vblock = VSCAT && (n0 >= 1536);
#pragma unroll
  for (int mi = 0; mi < 2; ++mi) {
    const int rowb = m0 + mi * 32 + 4 * lh;
#pragma unroll
    for (int ni = 0; ni < 2; ++ni) {
      const int col = n0 + (w * 2 + ni) * 32 + l31;
      const float bv = bias[col];
      if (!vblock) {
        const float mul = (col < sc_lim) ? sc : 1.f;
#pragma unroll
        for (int r = 0; r < 16; ++r) {
          const int row = rowb + (r & 3) + 8 * (r >> 2);
          float v = (acc[mi][ni][r] + bv) * mul;
          if (OUTF32)
            ((float*)Cout)[(size_t)row * N + col] = v;
          else
            ((unsigned short*)Cout)[(size_t)row * N + col] = f2bf(v);
        }
      } else {
        const int x = col - 1536;
        const int h = x / 96, d = x % 96;
#pragma unroll
        for (int r = 0; r < 16; ++r) {
          const int row = rowb + (r & 3) + 8 * (r >> 2);
          const int bb = row >> 10, t = row & 1023;
          vt[((size_t)(bb * H_ + h) * D_ + d) * T_ + t] =
              f2bf(acc[mi][ni][r] + bv);
        }
      }
    }
  }
}

// ---------------------------------------------------------------------------
// proj GEMM: SINGLE-WAVE (64 thr) blocks, tile 64x64, BK=32 dbuf — NO
// barriers at all. DMA->ds_read ordering via explicit s_waitcnt vmcnt(8)
// (waits iter-k loads, leaves iter-k+1's 8 loads in flight; m135 semantics);
// wave-internal program order + compiler lgkmcnt give RAW/WAR safety.
// Grid 1536 = 6/CU; 16 KB LDS -> residency-capped by dispatch only.
// ---------------------------------------------------------------------------
__global__ __launch_bounds__(64) void gemm1w_kernel(
    const unsigned short* __restrict__ A, const unsigned short* __restrict__ Bt,
    const float* __restrict__ bias, float* __restrict__ Cout, int N,
    int mmask, int mshift) {
  constexpr int NCH = 8;           // (2 A + 2 B blocks) * 2 kh
  __shared__ __align__(16) unsigned short Sb[2][NCH * 512];  // 16 KB
  const int l = threadIdx.x;
  const int l31 = l & 31, lh = l >> 5;
  const int bid = blockIdx.x;
  const int m0 = (bid & mmask) * 64, n0 = (bid >> mshift) * 64;

  f32x16 acc[2][2];
#pragma unroll
  for (int i = 0; i < 2; ++i)
#pragma unroll
    for (int j = 0; j < 2; ++j)
#pragma unroll
      for (int r = 0; r < 16; ++r) acc[i][j][r] = 0.f;

  const unsigned short* gp[NCH];
#pragma unroll
  for (int c = 0; c < NCH; ++c) {
    const int pr = c >> 1, kh = c & 1;
    gp[c] = (pr < 2)
        ? A  + (size_t)(m0 + pr * 32 + l31) * KD_ + kh * 16 + lh * 8
        : Bt + (size_t)(n0 + (pr - 2) * 32 + l31) * KD_ + kh * 16 + lh * 8;
  }

#pragma unroll
  for (int c = 0; c < NCH; ++c) {
    load_lds16(gp[c], &Sb[0][c * 512]);
    gp[c] += 32;
  }

  for (int k = 0; k < NIT; ++k) {
    const unsigned short* sb = Sb[k & 1];
    if (k + 1 < NIT) {
      unsigned short* nb = Sb[(k + 1) & 1];
#pragma unroll
      for (int c = 0; c < NCH; ++c) {
        load_lds16(gp[c], &nb[c * 512]);
        gp[c] += 32;
      }
      // iter-k's 8 loads done; iter-k+1's 8 newest stay in flight
      __asm__ __volatile__("s_waitcnt vmcnt(8)" ::: "memory");
    } else {
      __asm__ __volatile__("s_waitcnt vmcnt(0)" ::: "memory");
    }
#pragma unroll
    for (int kh = 0; kh < 2; ++kh) {
      bf16x8 af[2], bfr[2];
#pragma unroll
      for (int mi = 0; mi < 2; ++mi)
        af[mi] = *(const bf16x8*)&sb[(mi * 2 + kh) * 512 + l * 8];
#pragma unroll
      for (int ni = 0; ni < 2; ++ni)
        bfr[ni] = *(const bf16x8*)&sb[(4 + ni * 2 + kh) * 512 + l * 8];
#pragma unroll
      for (int mi = 0; mi < 2; ++mi)
#pragma unroll
        for (int ni = 0; ni < 2; ++ni)
          acc[mi][ni] = __builtin_amdgcn_mfma_f32_32x32x16_bf16(
              af[mi], bfr[ni], acc[mi][ni], 0, 0, 0);
    }
  }

#pragma unroll
  for (int mi = 0; mi < 2; ++mi) {
    const int rowb = m0 + mi * 32 + 4 * lh;
#pragma unroll
    for (int ni = 0; ni < 2; ++ni) {
      const int col = n0 + ni * 32 + l31;
      const float bv = bias[col];
#pragma unroll
      for (int r = 0; r < 16; ++r) {
        const int row = rowb + (r & 3) + 8 * (r >> 2);
        Cout[(size_t)row * N + col] = acc[mi][ni][r] + bv;
      }
    }
  }
}

// ---------------------------------------------------------------------------
// Flash causal attention (unchanged R8): bf16 MFMA 16x16x32, max-free softmax
// (Q pre-scaled), l via ones-MFMA, paired q-tiles (17 key-tiles/block),
// K/V double-buffered LDS, XCD swizzle bh = id & 63.
// ---------------------------------------------------------------------------
__global__ __launch_bounds__(256) void attn_mfma_kernel(
    const unsigned short* __restrict__ qkv,  // [8192][2304], Q pre-scaled
    const unsigned short* __restrict__ vt,   // [64][96][1024]
    unsigned short* __restrict__ y) {        // [8192][768]
  __shared__ __align__(16) unsigned short KV[2][24 * 512];  // 48 KB
  __shared__ __align__(16) unsigned short Pt[4][16][72];    // pad 64->72

  const int tid = threadIdx.x;
  const int w = tid >> 6, l = tid & 63;
  const int lm = l & 15, lq = l >> 4;
  const int bh = blockIdx.x & 63, pi = blockIdx.x >> 6;
  const int b = bh >> 3, h = bh & 7;
  const size_t bT = (size_t)b * T_;

  bf16x8 onef;
#pragma unroll
  for (int i = 0; i < 8; ++i) onef[i] = (__bf16)1.0f;

  auto issue = [&](int j0, int buf) {
#pragma unroll
    for (int i = 0; i < 6; ++i) {
      const int c = w * 6 + i;
      const unsigned short* g;
      if (c < 12) {
        const int kc = c >> 2, nb = c & 3;
        g = qkv + (bT + j0 + nb * 16 + lm) * N1_ + C_ + h * D_ + kc * 32 + lq * 8;
      } else {
        const int cv = c - 12;
        const int db = cv >> 1, vc = cv & 1;
        g = vt + ((size_t)bh * D_ + db * 16 + lm) * T_ + j0 + vc * 32 + lq * 8;
      }
      load_lds16(g, &KV[buf][c * 512]);
    }
  };

  int cur = 0;
  issue(0, 0);

  for (int half = 0; half < 2; ++half) {
    const int qt = half ? (15 - pi) : pi;
    const int q0 = qt * 64;

    bf16x8 qf[3];
    {
      const unsigned short* qp =
          qkv + (bT + q0 + w * 16 + lm) * N1_ + h * D_ + lq * 8;
      qf[0] = *(const bf16x8*)(qp);
      qf[1] = *(const bf16x8*)(qp + 32);
      qf[2] = *(const bf16x8*)(qp + 64);
    }
    f32x4 o[7];
#pragma unroll
    for (int i = 0; i < 7; ++i) o[i] = (f32x4){0.f, 0.f, 0.f, 0.f};

    for (int jt = 0; jt <= qt; ++jt) {
      __syncthreads();
      if (jt < qt)          issue((jt + 1) * 64, cur ^ 1);
      else if (half == 0)   issue(0, cur ^ 1);

      const bool diag = (jt == qt);
#pragma unroll
      for (int nb = 0; nb < 4; ++nb) {
        if (diag && nb > w) {
#pragma unroll
          for (int r = 0; r < 4; ++r)
            Pt[w][lq * 4 + r][nb * 16 + lm] = 0;
          continue;
        }
        f32x4 a = (f32x4){0.f, 0.f, 0.f, 0.f};
#pragma unroll
        for (int kc = 0; kc < 3; ++kc) {
          bf16x8 kf = *(const bf16x8*)&KV[cur][(kc * 4 + nb) * 512 + l * 8];
          a = __builtin_amdgcn_mfma_f32_16x16x32_bf16(qf[kc], kf, a, 0, 0, 0);
        }
#pragma unroll
        for (int r = 0; r < 4; ++r) {
          float s = a[r];
          if (diag && (nb * 16 + lm > w * 16 + lq * 4 + r)) s = -INFINITY;
          Pt[w][lq * 4 + r][nb * 16 + lm] = f2bf(__expf(s));
        }
      }

      bf16x8 pf0 = *(const bf16x8*)&Pt[w][lm][lq * 8];
      bf16x8 pf1 = *(const bf16x8*)&Pt[w][lm][32 + lq * 8];
#pragma unroll
      for (int db = 0; db < 6; ++db) {
        bf16x8 vf0 = *(const bf16x8*)&KV[cur][(12 + db * 2 + 0) * 512 + l * 8];
        bf16x8 vf1 = *(const bf16x8*)&KV[cur][(12 + db * 2 + 1) * 512 + l * 8];
        o[db] = __builtin_amdgcn_mfma_f32_16x16x32_bf16(pf0, vf0, o[db], 0, 0, 0);
        o[db] = __builtin_amdgcn_mfma_f32_16x16x32_bf16(pf1, vf1, o[db], 0, 0, 0);
      }
      o[6] = __builtin_amdgcn_mfma_f32_16x16x32_bf16(pf0, onef, o[6], 0, 0, 0);
      o[6] = __builtin_amdgcn_mfma_f32_16x16x32_bf16(pf1, onef, o[6], 0, 0, 0);
      cur ^= 1;
    }

#pragma unroll
    for (int r = 0; r < 4; ++r) {
      const float inv = 1.f / o[6][r];
      const size_t row = bT + q0 + w * 16 + lq * 4 + r;
#pragma unroll
      for (int db = 0; db < 6; ++db)
        y[row * C_ + h * D_ + db * 16 + lm] = f2bf(o[db][r] * inv);
    }
  }
}

// ---------------------------------------------------------------------------
extern "C" void kernel_launch(void* const* d_in, const int* in_sizes, int n_in,
                              void* d_out, int out_size, void* d_ws, size_t ws_size,
                              hipStream_t stream) {
  const float* x      = (const float*)d_in[0];
  const float* W_attn = (const float*)d_in[1];
  const float* b_attn = (const float*)d_in[2];
  const float* W_proj = (const float*)d_in[3];
  const float* b_proj = (const float*)d_in[4];
  float* out = (float*)d_out;

  char* ws = (char*)d_ws;
  unsigned short* xb  = (unsigned short*)(ws);                    // 12.58 MB
  unsigned short* WaT = (unsigned short*)(ws + 12582912);         //  3.54 MB
  unsigned short* WpT = (unsigned short*)(ws + 16121856);         //  1.18 MB
  unsigned short* qkv = (unsigned short*)(ws + 17301504);         // 37.75 MB
  unsigned short* vt  = (unsigned short*)(ws + 55050240);         // 12.58 MB
  unsigned short* yb  = (unsigned short*)(ws + 67633152);         // 12.58 MB

  const float qscale = 0.10206207261596577f;  // 1/sqrt(96)

  cvt_bf16_kernel<<<(M_ * C_) / 1024, 256, 0, stream>>>(x, xb, M_ * C_);
  w_transpose2_kernel<<<2304, 256, 0, stream>>>(W_attn, WaT, W_proj, WpT);

  // qkv: 2304 blocks of 128 thr (tile 64x128), swizzle m-panel = bid & 127
  gemm2w_kernel<false, true><<<(N1_ / 128) * (M_ / 64), 128, 0, stream>>>(
      xb, WaT, b_attn, qkv, vt, N1_, C_, qscale, 127, 7);
  // attn: 512 blocks, bh = id & 63 for XCD locality
  attn_mfma_kernel<<<8 * B_ * H_, 256, 0, stream>>>(qkv, vt, yb);
  // proj: 1536 single-wave blocks (tile 64x64), barrier-free
  gemm1w_kernel<<<(C_ / 64) * (M_ / 64), 64, 0, stream>>>(
      yb, WpT, b_proj, out, C_, 127, 7);
}

// Round 13
// 218.365 us; speedup vs baseline: 1.8659x; 1.1389x over previous
//
#include <hip/hip_runtime.h>
#include <math.h>

#define B_ 8
#define T_ 1024
#define C_ 768
#define H_ 8
#define D_ 96
#define M_ (B_ * T_)     // 8192 tokens
#define N1_ (3 * C_)     // 2304
#define KD_ 768          // K of both GEMMs

typedef __bf16 bf16x8 __attribute__((ext_vector_type(8)));
typedef float f32x4 __attribute__((ext_vector_type(4)));
typedef float f32x16 __attribute__((ext_vector_type(16)));

__device__ __forceinline__ unsigned short f2bf(float f) {
  unsigned int u = __float_as_uint(f);
  u += 0x7FFF + ((u >> 16) & 1);          // round-to-nearest-even
  return (unsigned short)(u >> 16);
}

// async global->LDS, 16B per lane; LDS dest = uniform base + lane*16
__device__ __forceinline__ void load_lds16(const void* g, void* l) {
  __builtin_amdgcn_global_load_lds(
      (const __attribute__((address_space(1))) unsigned int*)g,
      (__attribute__((address_space(3))) unsigned int*)l, 16, 0, 0);
}

// ---------------------------------------------------------------------------
// Fused prep: blocks 0..6143 cast x to bf16 (1024 elems each);
// blocks 6144.. transpose W_attn / W_proj to [N][K] bf16.
// ---------------------------------------------------------------------------
__global__ __launch_bounds__(256) void prep_kernel(
    const float* __restrict__ x, unsigned short* __restrict__ xb,
    const float* __restrict__ Wa, unsigned short* __restrict__ WaT,
    const float* __restrict__ Wp, unsigned short* __restrict__ WpT) {
  __shared__ float Lt[32][33];
  int bid = blockIdx.x;
  if (bid < 6144) {
    int i = (bid * 256 + threadIdx.x) * 4;
    float4 v = *(const float4*)(x + i);
    ushort4 o;
    o.x = f2bf(v.x); o.y = f2bf(v.y); o.z = f2bf(v.z); o.w = f2bf(v.w);
    *(ushort4*)(xb + i) = o;
    return;
  }
  bid -= 6144;
  const float* W; unsigned short* WT; int Nd;
  if (bid < 1728) { W = Wa; WT = WaT; Nd = N1_; }
  else            { W = Wp; WT = WpT; Nd = C_; bid -= 1728; }
  const int r0 = (bid % 24) * 32;   // Kd
  const int c0 = (bid / 24) * 32;   // Nd
#pragma unroll
  for (int i = 0; i < 4; ++i) {
    int e = threadIdx.x + 256 * i;
    int r = e >> 5, c = e & 31;
    Lt[r][c] = W[(size_t)(r0 + r) * Nd + c0 + c];
  }
  __syncthreads();
#pragma unroll
  for (int i = 0; i < 4; ++i) {
    int e = threadIdx.x + 256 * i;
    int rr = e >> 5, cc = e & 31;
    WT[(size_t)(c0 + rr) * KD_ + r0 + cc] = f2bf(Lt[cc][rr]);
  }
}

// ---------------------------------------------------------------------------
// bf16 MFMA GEMM (R8 structure): 32x32x16, dbuf LDS BK=32, load_lds staging.
// __launch_bounds__(256, 4): cap combined VGPR+AGPR at ~128/wave so 4 blocks
// fit per CU (R8 ran 132 regs -> 3.8 waves/SIMD -> 2.5 resident; the DMA
// chain per block is latency-bound ~10 GB/s, so throughput ~ resident blocks).
// Tile (2*WM32*32) x 128. A/B frag: lane l = [row=l&31][k=(l>>5)*8..+7].
// C/D: col = lane&31, row = (r&3)+8*(r>>2)+4*(lane>>5)  [m74/m101].
// VSCAT (qkv): cols >= 1536 (V) scatter to vt[bh][d][t].
// Grid 1-D, XCD swizzle: m-panel = bid & mmask.
// ---------------------------------------------------------------------------
template <int WM32, bool OUTF32, bool VSCAT>
__global__ __launch_bounds__(256, 4) void gemm_mfma_kernel(
    const unsigned short* __restrict__ A, const unsigned short* __restrict__ Bt,
    const float* __restrict__ bias, void* __restrict__ Cout,
    unsigned short* __restrict__ vt, int N,
    int sc_lim, float sc, int mmask, int mshift) {
  constexpr int AS2 = 2 * WM32;        // A 32-row blocks per tile
  constexpr int NCH = AS2 * 2 + 8;     // 1KB chunks per buffer
  constexpr int CPW = NCH / 4;         // chunks staged per wave
  __shared__ __align__(16) unsigned short Sb[2][NCH * 512];
  const int tid = threadIdx.x;
  const int w = tid >> 6, l = tid & 63;
  const int l31 = l & 31, lh = l >> 5;
  const int bid = blockIdx.x;
  const int m0 = (bid & mmask) * (AS2 * 32), n0 = (bid >> mshift) * 128;
  const int wrb = (w >> 1) * WM32;     // wave A-block base
  const int wnb = (w & 1) * 2;         // wave B-block base

  f32x16 acc[WM32][2];
#pragma unroll
  for (int i = 0; i < WM32; ++i)
#pragma unroll
    for (int j = 0; j < 2; ++j)
#pragma unroll
      for (int r = 0; r < 16; ++r) acc[i][j][r] = 0.f;

  const unsigned short* gp[CPW];
#pragma unroll
  for (int i = 0; i < CPW; ++i) {
    const int c = w * CPW + i;
    const int pr = c >> 1, kh = c & 1;
    gp[i] = (pr < AS2)
        ? A  + (size_t)(m0 + pr * 32 + l31) * KD_ + kh * 16 + lh * 8
        : Bt + (size_t)(n0 + (pr - AS2) * 32 + l31) * KD_ + kh * 16 + lh * 8;
  }

  // prologue: stage k0=0 into buffer 0
#pragma unroll
  for (int i = 0; i < CPW; ++i) {
    load_lds16(gp[i], &Sb[0][(w * CPW + i) * 512]);
    gp[i] += 32;
  }

  int cur = 0;
  for (int k0 = 0; k0 < KD_; k0 += 32) {
    __syncthreads();  // buf[cur] ready; prev compute done
    if (k0 + 32 < KD_) {
#pragma unroll
      for (int i = 0; i < CPW; ++i) {
        load_lds16(gp[i], &Sb[cur ^ 1][(w * CPW + i) * 512]);
        gp[i] += 32;
      }
    }
#pragma unroll
    for (int kh = 0; kh < 2; ++kh) {
      bf16x8 af[WM32], bfr[2];
#pragma unroll
      for (int mi = 0; mi < WM32; ++mi)
        af[mi] = *(const bf16x8*)&Sb[cur][((wrb + mi) * 2 + kh) * 512 + l * 8];
#pragma unroll
      for (int ni = 0; ni < 2; ++ni)
        bfr[ni] = *(const bf16x8*)&Sb[cur][((AS2 + wnb + ni) * 2 + kh) * 512 + l * 8];
#pragma unroll
      for (int mi = 0; mi < WM32; ++mi)
#pragma unroll
        for (int ni = 0; ni < 2; ++ni)
          acc[mi][ni] = __builtin_amdgcn_mfma_f32_32x32x16_bf16(
              af[mi], bfr[ni], acc[mi][ni], 0, 0, 0);
    }
    cur ^= 1;
  }

  const bool vblock = VSCAT && (n0 >= 1536);
#pragma unroll
  for (int mi = 0; mi < WM32; ++mi) {
    const int rowb = m0 + (wrb + mi) * 32 + 4 * lh;
#pragma unroll
    for (int ni = 0; ni < 2; ++ni) {
      const int col = n0 + (wnb + ni) * 32 + l31;
      const float bv = bias[col];
      if (!vblock) {
        const float mul = (col < sc_lim) ? sc : 1.f;
#pragma unroll
        for (int r = 0; r < 16; ++r) {
          const int row = rowb + (r & 3) + 8 * (r >> 2);
          float v = (acc[mi][ni][r] + bv) * mul;
          if (OUTF32)
            ((float*)Cout)[(size_t)row * N + col] = v;
          else
            ((unsigned short*)Cout)[(size_t)row * N + col] = f2bf(v);
        }
      } else {
        const int x = col - 1536;
        const int h = x / 96, d = x % 96;
#pragma unroll
        for (int r = 0; r < 16; ++r) {
          const int row = rowb + (r & 3) + 8 * (r >> 2);
          const int bb = row >> 10, t = row & 1023;
          vt[((size_t)(bb * H_ + h) * D_ + d) * T_ + t] =
              f2bf(acc[mi][ni][r] + bv);
        }
      }
    }
  }
}

// ---------------------------------------------------------------------------
// Flash causal attention (unchanged R8): bf16 MFMA 16x16x32, max-free softmax
// (Q pre-scaled), l via ones-MFMA, paired q-tiles (17 key-tiles/block),
// K/V double-buffered LDS, XCD swizzle bh = id & 63.
// ---------------------------------------------------------------------------
__global__ __launch_bounds__(256) void attn_mfma_kernel(
    const unsigned short* __restrict__ qkv,  // [8192][2304], Q pre-scaled
    const unsigned short* __restrict__ vt,   // [64][96][1024]
    unsigned short* __restrict__ y) {        // [8192][768]
  __shared__ __align__(16) unsigned short KV[2][24 * 512];  // 48 KB
  __shared__ __align__(16) unsigned short Pt[4][16][72];    // pad 64->72

  const int tid = threadIdx.x;
  const int w = tid >> 6, l = tid & 63;
  const int lm = l & 15, lq = l >> 4;
  const int bh = blockIdx.x & 63, pi = blockIdx.x >> 6;
  const int b = bh >> 3, h = bh & 7;
  const size_t bT = (size_t)b * T_;

  bf16x8 onef;
#pragma unroll
  for (int i = 0; i < 8; ++i) onef[i] = (__bf16)1.0f;

  auto issue = [&](int j0, int buf) {
#pragma unroll
    for (int i = 0; i < 6; ++i) {
      const int c = w * 6 + i;
      const unsigned short* g;
      if (c < 12) {
        const int kc = c >> 2, nb = c & 3;
        g = qkv + (bT + j0 + nb * 16 + lm) * N1_ + C_ + h * D_ + kc * 32 + lq * 8;
      } else {
        const int cv = c - 12;
        const int db = cv >> 1, vc = cv & 1;
        g = vt + ((size_t)bh * D_ + db * 16 + lm) * T_ + j0 + vc * 32 + lq * 8;
      }
      load_lds16(g, &KV[buf][c * 512]);
    }
  };

  int cur = 0;
  issue(0, 0);

  for (int half = 0; half < 2; ++half) {
    const int qt = half ? (15 - pi) : pi;
    const int q0 = qt * 64;

    bf16x8 qf[3];
    {
      const unsigned short* qp =
          qkv + (bT + q0 + w * 16 + lm) * N1_ + h * D_ + lq * 8;
      qf[0] = *(const bf16x8*)(qp);
      qf[1] = *(const bf16x8*)(qp + 32);
      qf[2] = *(const bf16x8*)(qp + 64);
    }
    f32x4 o[7];
#pragma unroll
    for (int i = 0; i < 7; ++i) o[i] = (f32x4){0.f, 0.f, 0.f, 0.f};

    for (int jt = 0; jt <= qt; ++jt) {
      __syncthreads();
      if (jt < qt)          issue((jt + 1) * 64, cur ^ 1);
      else if (half == 0)   issue(0, cur ^ 1);

      const bool diag = (jt == qt);
#pragma unroll
      for (int nb = 0; nb < 4; ++nb) {
        if (diag && nb > w) {
#pragma unroll
          for (int r = 0; r < 4; ++r)
            Pt[w][lq * 4 + r][nb * 16 + lm] = 0;
          continue;
        }
        f32x4 a = (f32x4){0.f, 0.f, 0.f, 0.f};
#pragma unroll
        for (int kc = 0; kc < 3; ++kc) {
          bf16x8 kf = *(const bf16x8*)&KV[cur][(kc * 4 + nb) * 512 + l * 8];
          a = __builtin_amdgcn_mfma_f32_16x16x32_bf16(qf[kc], kf, a, 0, 0, 0);
        }
#pragma unroll
        for (int r = 0; r < 4; ++r) {
          float s = a[r];
          if (diag && (nb * 16 + lm > w * 16 + lq * 4 + r)) s = -INFINITY;
          Pt[w][lq * 4 + r][nb * 16 + lm] = f2bf(__expf(s));
        }
      }

      bf16x8 pf0 = *(const bf16x8*)&Pt[w][lm][lq * 8];
      bf16x8 pf1 = *(const bf16x8*)&Pt[w][lm][32 + lq * 8];
#pragma unroll
      for (int db = 0; db < 6; ++db) {
        bf16x8 vf0 = *(const bf16x8*)&KV[cur][(12 + db * 2 + 0) * 512 + l * 8];
        bf16x8 vf1 = *(const bf16x8*)&KV[cur][(12 + db * 2 + 1) * 512 + l * 8];
        o[db] = __builtin_amdgcn_mfma_f32_16x16x32_bf16(pf0, vf0, o[db], 0, 0, 0);
        o[db] = __builtin_amdgcn_mfma_f32_16x16x32_bf16(pf1, vf1, o[db], 0, 0, 0);
      }
      o[6] = __builtin_amdgcn_mfma_f32_16x16x32_bf16(pf0, onef, o[6], 0, 0, 0);
      o[6] = __builtin_amdgcn_mfma_f32_16x16x32_bf16(pf1, onef, o[6], 0, 0, 0);
      cur ^= 1;
    }

#pragma unroll
    for (int r = 0; r < 4; ++r) {
      const float inv = 1.f / o[6][r];
      const size_t row = bT + q0 + w * 16 + lq * 4 + r;
#pragma unroll
      for (int db = 0; db < 6; ++db)
        y[row * C_ + h * D_ + db * 16 + lm] = f2bf(o[db][r] * inv);
    }
  }
}

// ---------------------------------------------------------------------------
extern "C" void kernel_launch(void* const* d_in, const int* in_sizes, int n_in,
                              void* d_out, int out_size, void* d_ws, size_t ws_size,
                              hipStream_t stream) {
  const float* x      = (const float*)d_in[0];
  const float* W_attn = (const float*)d_in[1];
  const float* b_attn = (const float*)d_in[2];
  const float* W_proj = (const float*)d_in[3];
  const float* b_proj = (const float*)d_in[4];
  float* out = (float*)d_out;

  char* ws = (char*)d_ws;
  unsigned short* xb  = (unsigned short*)(ws);                    // 12.58 MB
  unsigned short* WaT = (unsigned short*)(ws + 12582912);         //  3.54 MB
  unsigned short* WpT = (unsigned short*)(ws + 16121856);         //  1.18 MB
  unsigned short* qkv = (unsigned short*)(ws + 17301504);         // 37.75 MB
  unsigned short* vt  = (unsigned short*)(ws + 55050240);         // 12.58 MB
  unsigned short* yb  = (unsigned short*)(ws + 67633152);         // 12.58 MB

  const float qscale = 0.10206207261596577f;  // 1/sqrt(96)

  // fused prep: x cast (6144 blocks) + both W transposes (2304 blocks)
  prep_kernel<<<6144 + 2304, 256, 0, stream>>>(x, xb, W_attn, WaT, W_proj, WpT);

  // qkv = x @ W_attn + b_attn (Q cols pre-scaled; V cols scattered to vt)
  gemm_mfma_kernel<2, false, true><<<(N1_ / 128) * (M_ / 128), 256, 0, stream>>>(
      xb, WaT, b_attn, qkv, vt, N1_, C_, qscale, 63, 6);
  // attn: 512 blocks, bh = id & 63 for XCD locality
  attn_mfma_kernel<<<8 * B_ * H_, 256, 0, stream>>>(qkv, vt, yb);
  // proj: 64x128 tiles, 128 m-panels
  gemm_mfma_kernel<1, true, false><<<(C_ / 128) * (M_ / 64), 256, 0, stream>>>(
      yb, WpT, b_proj, out, nullptr, C_, 0, 1.f, 127, 7);
}